// Round 2
// baseline (2869.411 us; speedup 1.0000x reference)
//
#include <hip/hip_runtime.h>

#define N_USER   300000
#define M_ITEM   700000
#define N_NODES  (N_USER + M_ITEM)
#define DIM      64
#define N_EDGES  1200000
#define BATCH    4096
#define NLAYERS  3   // stacked has NLAYERS+1 = 4 entries

// ---------------------------------------------------------------------------
// Threefry2x32-20, JAX *partitionable* path (modern default):
//   per element i: counter words (hi, lo) = (0, i); key = (0, 42)
//   x0 = hi + k0, x1 = lo + k1; 20 rounds; bits = x0_out ^ x1_out
//   u = bitcast((bits >> 9) | 0x3F800000) - 1.0 ; keep = u >= 0.1
// ---------------------------------------------------------------------------
__device__ __forceinline__ unsigned rotl32(unsigned x, int r) {
    return (x << r) | (x >> (32 - r));
}

__global__ void dropout_vals_kernel(const float* __restrict__ edge_vals,
                                    float* __restrict__ vals_eff) {
    int i = blockIdx.x * blockDim.x + threadIdx.x;
    if (i >= N_EDGES) return;

    const unsigned k0 = 0u, k1 = 42u;
    unsigned ks[3] = {k0, k1, k0 ^ k1 ^ 0x1BD11BDAu};

    unsigned x0 = 0u + ks[0];            // hi word of 64-bit iota = 0
    unsigned x1 = (unsigned)i + ks[1];   // lo word = i

    const int rotA[4] = {13, 15, 26, 6};
    const int rotB[4] = {17, 29, 16, 24};
#pragma unroll
    for (int g = 0; g < 5; ++g) {
#pragma unroll
        for (int j = 0; j < 4; ++j) {
            int r = (g & 1) ? rotB[j] : rotA[j];
            x0 += x1;
            x1 = rotl32(x1, r);
            x1 ^= x0;
        }
        x0 += ks[(g + 1) % 3];
        x1 += ks[(g + 2) % 3] + (unsigned)(g + 1);
    }

    unsigned bits = x0 ^ x1;  // partitionable 32-bit output
    float u = __uint_as_float((bits >> 9) | 0x3F800000u) - 1.0f;
    vals_eff[i] = (u >= 0.1f) ? edge_vals[i] / 0.9f : 0.0f;
}

// ---------------------------------------------------------------------------
// SpMM: out[dst] += val * src_emb[src], 16 threads/edge, float4 per thread.
// ---------------------------------------------------------------------------
__global__ void spmm_atomic_kernel(const float* __restrict__ src_user,
                                   const float* __restrict__ src_item,
                                   const int* __restrict__ esrc,
                                   const int* __restrict__ edst,
                                   const float* __restrict__ vals,
                                   float* __restrict__ out) {
    int t = blockIdx.x * blockDim.x + threadIdx.x;
    int e = t >> 4;
    if (e >= N_EDGES) return;
    float v = vals[e];
    if (v == 0.0f) return;  // dropped edge contributes nothing

    int c = (t & 15) << 2;  // dim offset (float4 chunk)
    int s = esrc[e];
    int d = edst[e];
    const float* srow = (s < N_USER) ? (src_user + (size_t)s * DIM)
                                     : (src_item + (size_t)(s - N_USER) * DIM);
    float4 x = *(const float4*)(srow + c);
    float* drow = out + (size_t)d * DIM + c;
    atomicAdd(drow + 0, v * x.x);
    atomicAdd(drow + 1, v * x.y);
    atomicAdd(drow + 2, v * x.z);
    atomicAdd(drow + 3, v * x.w);
}

// ---------------------------------------------------------------------------
// Per-layer extraction of sampled user/item rows.
// ---------------------------------------------------------------------------
__global__ void extract_layer_kernel(const float* __restrict__ emb_u,
                                     const float* __restrict__ emb_i,
                                     const int* __restrict__ users,
                                     const int* __restrict__ items,
                                     float* __restrict__ inter_layers,
                                     float* __restrict__ u_sum,
                                     float* __restrict__ i_sum,
                                     int layer) {
    int b = blockIdx.x * 4 + (threadIdx.x >> 6);
    int d = threadIdx.x & 63;
    if (b >= BATCH) return;
    float u  = emb_u[(size_t)users[b] * DIM + d];
    float it = emb_i[(size_t)items[b] * DIM + d];
    inter_layers[((size_t)b * (NLAYERS + 1) + layer) * DIM + d] = u * it;
    size_t idx = (size_t)b * DIM + d;
    if (layer == 0) {
        u_sum[idx] = u;
        i_sum[idx] = it;
    } else {
        u_sum[idx] += u;
        i_sum[idx] += it;
    }
}

// ---------------------------------------------------------------------------
// Final pooling: light = sum/4, inter = lu*li, ratings = sigmoid(sum_d inter)
// ---------------------------------------------------------------------------
__global__ void finalize_kernel(const float* __restrict__ u_sum,
                                const float* __restrict__ i_sum,
                                float* __restrict__ ratings,
                                float* __restrict__ inter) {
    int b = blockIdx.x * 4 + (threadIdx.x >> 6);
    int d = threadIdx.x & 63;
    if (b >= BATCH) return;
    size_t idx = (size_t)b * DIM + d;
    float lu = u_sum[idx] * 0.25f;
    float li = i_sum[idx] * 0.25f;
    float p = lu * li;
    inter[idx] = p;
    float s = p;
#pragma unroll
    for (int off = 32; off > 0; off >>= 1) s += __shfl_down(s, off, 64);
    if (d == 0) ratings[b] = 1.0f / (1.0f + expf(-s));
}

// ---------------------------------------------------------------------------
extern "C" void kernel_launch(void* const* d_in, const int* in_sizes, int n_in,
                              void* d_out, int out_size, void* d_ws, size_t ws_size,
                              hipStream_t stream) {
    const float* user_emb  = (const float*)d_in[0];
    const float* item_emb  = (const float*)d_in[1];
    const float* edge_vals = (const float*)d_in[2];
    const int*   edge_src  = (const int*)d_in[3];
    const int*   edge_dst  = (const int*)d_in[4];
    const int*   users     = (const int*)d_in[5];
    const int*   items     = (const int*)d_in[6];

    float* out          = (float*)d_out;
    float* ratings      = out;                       // [BATCH]
    float* inter        = out + BATCH;               // [BATCH, DIM]
    float* inter_layers = out + BATCH + BATCH * DIM; // [BATCH, 4, DIM]

    const size_t node_buf_bytes = (size_t)N_NODES * DIM * sizeof(float); // 256 MB
    char* ws = (char*)d_ws;
    float* bufA  = (float*)ws;
    float* bufB  = (float*)(ws + node_buf_bytes);
    float* vals  = (float*)(ws + 2 * node_buf_bytes);
    float* u_sum = vals + N_EDGES;
    float* i_sum = u_sum + BATCH * DIM;

    const int spmm_threads = N_EDGES * 16;
    const dim3 spmm_grid((spmm_threads + 255) / 256);
    const dim3 blk(256);
    const dim3 ext_grid(BATCH / 4);

    // 1. dropout-scaled edge values (bit-exact partitionable threefry)
    dropout_vals_kernel<<<(N_EDGES + 255) / 256, blk, 0, stream>>>(edge_vals, vals);

    // 2. layer 0 extraction (reads original embeddings, inits sums)
    extract_layer_kernel<<<ext_grid, blk, 0, stream>>>(
        user_emb, item_emb, users, items, inter_layers, u_sum, i_sum, 0);

    // 3. layer 1: (user_emb ++ item_emb) -> bufA
    hipMemsetAsync(bufA, 0, node_buf_bytes, stream);
    spmm_atomic_kernel<<<spmm_grid, blk, 0, stream>>>(
        user_emb, item_emb, edge_src, edge_dst, vals, bufA);
    extract_layer_kernel<<<ext_grid, blk, 0, stream>>>(
        bufA, bufA + (size_t)N_USER * DIM, users, items, inter_layers, u_sum, i_sum, 1);

    // 4. layer 2: bufA -> bufB
    hipMemsetAsync(bufB, 0, node_buf_bytes, stream);
    spmm_atomic_kernel<<<spmm_grid, blk, 0, stream>>>(
        bufA, bufA + (size_t)N_USER * DIM, edge_src, edge_dst, vals, bufB);
    extract_layer_kernel<<<ext_grid, blk, 0, stream>>>(
        bufB, bufB + (size_t)N_USER * DIM, users, items, inter_layers, u_sum, i_sum, 2);

    // 5. layer 3: bufB -> bufA (layer-1 data already extracted; safe to reuse)
    hipMemsetAsync(bufA, 0, node_buf_bytes, stream);
    spmm_atomic_kernel<<<spmm_grid, blk, 0, stream>>>(
        bufB, bufB + (size_t)N_USER * DIM, edge_src, edge_dst, vals, bufA);
    extract_layer_kernel<<<ext_grid, blk, 0, stream>>>(
        bufA, bufA + (size_t)N_USER * DIM, users, items, inter_layers, u_sum, i_sum, 3);

    // 6. pooling + ratings
    finalize_kernel<<<ext_grid, blk, 0, stream>>>(u_sum, i_sum, ratings, inter);
}

// Round 3
// 754.220 us; speedup vs baseline: 3.8045x; 3.8045x over previous
//
#include <hip/hip_runtime.h>

#define N_USER   300000
#define M_ITEM   700000
#define N_NODES  (N_USER + M_ITEM)
#define DIM      64
#define N_EDGES  1200000
#define BATCH    4096
#define NLAYERS  3   // stacked has NLAYERS+1 = 4 entries

#define SCAN_CHUNK 1024
#define NB_SCAN    ((N_NODES + SCAN_CHUNK - 1) / SCAN_CHUNK)  // 977

// ---------------------------------------------------------------------------
// CSR build: histogram over dst -> exclusive scan -> scatter (with threefry
// dropout folded in). 2.4M int atomics once, reused by all 3 SpMM layers.
// ---------------------------------------------------------------------------
__global__ void hist_kernel(const int* __restrict__ edst, int* __restrict__ deg) {
    int e = blockIdx.x * blockDim.x + threadIdx.x;
    if (e < N_EDGES) atomicAdd(&deg[edst[e]], 1);
}

// per-block exclusive prefix into pre[], block totals into blockSums[]
__global__ void scan1_kernel(const int* __restrict__ deg, int* __restrict__ pre,
                             int* __restrict__ blockSums) {
    int b = blockIdx.x, t = threadIdx.x;  // 256 threads, 4 elems each
    int base = b * SCAN_CHUNK + t * 4;
    int v[4];
#pragma unroll
    for (int j = 0; j < 4; ++j) {
        int i = base + j;
        v[j] = (i < N_NODES) ? deg[i] : 0;
    }
    int s = v[0] + v[1] + v[2] + v[3];
    int lane = t & 63, w = t >> 6;
    int x = s;
#pragma unroll
    for (int off = 1; off < 64; off <<= 1) {
        int y = __shfl_up(x, off, 64);
        if (lane >= off) x += y;
    }
    __shared__ int wsum[4];
    if (lane == 63) wsum[w] = x;
    __syncthreads();
    int woff = 0;
    for (int i = 0; i < w; ++i) woff += wsum[i];
    int run = woff + (x - s);  // exclusive prefix of this thread's first elem
#pragma unroll
    for (int j = 0; j < 4; ++j) {
        int i = base + j;
        if (i < N_NODES) pre[i] = run;
        run += v[j];
    }
    if (t == 255) blockSums[b] = wsum[0] + wsum[1] + wsum[2] + wsum[3];
}

// single-block exclusive scan of the 977 block totals
__global__ void scan2_kernel(int* __restrict__ blockSums) {
    __shared__ int sm[1024];
    int t = threadIdx.x;
    int v = (t < NB_SCAN) ? blockSums[t] : 0;
    sm[t] = v;
    __syncthreads();
    for (int off = 1; off < 1024; off <<= 1) {
        int y = (t >= off) ? sm[t - off] : 0;
        __syncthreads();
        sm[t] += y;
        __syncthreads();
    }
    if (t < NB_SCAN) blockSums[t] = sm[t] - v;  // exclusive
}

// add block offsets in-place -> row_ptr; init fill[] with same values
__global__ void scan3_kernel(int* __restrict__ row_ptr,
                             const int* __restrict__ blockSums,
                             int* __restrict__ fill) {
    int i = blockIdx.x * blockDim.x + threadIdx.x;
    if (i < N_NODES) {
        int r = row_ptr[i] + blockSums[i >> 10];
        row_ptr[i] = r;
        fill[i] = r;
    }
    if (i == 0) row_ptr[N_NODES] = N_EDGES;
}

// ---------------------------------------------------------------------------
// Threefry2x32-20, JAX partitionable path (verified round 2) folded into the
// CSR scatter: csr_val = keep ? val/0.9 : 0
// ---------------------------------------------------------------------------
__device__ __forceinline__ unsigned rotl32(unsigned x, int r) {
    return (x << r) | (x >> (32 - r));
}

__global__ void scatter_kernel(const float* __restrict__ edge_vals,
                               const int* __restrict__ esrc,
                               const int* __restrict__ edst,
                               int* __restrict__ fill,
                               int* __restrict__ csr_src,
                               float* __restrict__ csr_val) {
    int e = blockIdx.x * blockDim.x + threadIdx.x;
    if (e >= N_EDGES) return;

    unsigned ks[3] = {0u, 42u, 0u ^ 42u ^ 0x1BD11BDAu};
    unsigned x0 = ks[0];                 // hi word of 64-bit iota = 0
    unsigned x1 = (unsigned)e + ks[1];   // lo word = e
    const int rotA[4] = {13, 15, 26, 6};
    const int rotB[4] = {17, 29, 16, 24};
#pragma unroll
    for (int g = 0; g < 5; ++g) {
#pragma unroll
        for (int j = 0; j < 4; ++j) {
            int r = (g & 1) ? rotB[j] : rotA[j];
            x0 += x1;
            x1 = rotl32(x1, r);
            x1 ^= x0;
        }
        x0 += ks[(g + 1) % 3];
        x1 += ks[(g + 2) % 3] + (unsigned)(g + 1);
    }
    unsigned bits = x0 ^ x1;
    float u = __uint_as_float((bits >> 9) | 0x3F800000u) - 1.0f;
    float veff = (u >= 0.1f) ? edge_vals[e] * (1.0f / 0.9f) : 0.0f;

    int d = edst[e];
    int pos = atomicAdd(&fill[d], 1);
    csr_src[pos] = esrc[e];
    csr_val[pos] = veff;
}

// ---------------------------------------------------------------------------
// CSR SpMM: 16 threads per dst node, one float4 chunk each; register
// accumulate over incident edges; single store. No atomics, no memset.
// ---------------------------------------------------------------------------
__global__ void spmm_csr_kernel(const float* __restrict__ src_user,
                                const float* __restrict__ src_item,
                                const int* __restrict__ row_ptr,
                                const int* __restrict__ csr_src,
                                const float* __restrict__ csr_val,
                                float* __restrict__ out) {
    int t = blockIdx.x * blockDim.x + threadIdx.x;
    int n = t >> 4;
    if (n >= N_NODES) return;
    int c = (t & 15) << 2;
    int k0 = row_ptr[n], k1 = row_ptr[n + 1];
    float4 acc = {0.f, 0.f, 0.f, 0.f};
    for (int k = k0; k < k1; ++k) {
        float v = csr_val[k];
        if (v == 0.0f) continue;  // dropped edge
        int s = csr_src[k];
        const float* srow = (s < N_USER) ? (src_user + (size_t)s * DIM)
                                         : (src_item + (size_t)(s - N_USER) * DIM);
        float4 x = *(const float4*)(srow + c);
        acc.x += v * x.x;
        acc.y += v * x.y;
        acc.z += v * x.z;
        acc.w += v * x.w;
    }
    *(float4*)(out + (size_t)n * DIM + c) = acc;
}

// ---------------------------------------------------------------------------
// Per-layer extraction of sampled user/item rows.
// ---------------------------------------------------------------------------
__global__ void extract_layer_kernel(const float* __restrict__ emb_u,
                                     const float* __restrict__ emb_i,
                                     const int* __restrict__ users,
                                     const int* __restrict__ items,
                                     float* __restrict__ inter_layers,
                                     float* __restrict__ u_sum,
                                     float* __restrict__ i_sum,
                                     int layer) {
    int b = blockIdx.x * 4 + (threadIdx.x >> 6);
    int d = threadIdx.x & 63;
    if (b >= BATCH) return;
    float u  = emb_u[(size_t)users[b] * DIM + d];
    float it = emb_i[(size_t)items[b] * DIM + d];
    inter_layers[((size_t)b * (NLAYERS + 1) + layer) * DIM + d] = u * it;
    size_t idx = (size_t)b * DIM + d;
    if (layer == 0) {
        u_sum[idx] = u;
        i_sum[idx] = it;
    } else {
        u_sum[idx] += u;
        i_sum[idx] += it;
    }
}

// ---------------------------------------------------------------------------
// Final pooling: light = sum/4, inter = lu*li, ratings = sigmoid(sum_d inter)
// ---------------------------------------------------------------------------
__global__ void finalize_kernel(const float* __restrict__ u_sum,
                                const float* __restrict__ i_sum,
                                float* __restrict__ ratings,
                                float* __restrict__ inter) {
    int b = blockIdx.x * 4 + (threadIdx.x >> 6);
    int d = threadIdx.x & 63;
    if (b >= BATCH) return;
    size_t idx = (size_t)b * DIM + d;
    float lu = u_sum[idx] * 0.25f;
    float li = i_sum[idx] * 0.25f;
    float p = lu * li;
    inter[idx] = p;
    float s = p;
#pragma unroll
    for (int off = 32; off > 0; off >>= 1) s += __shfl_down(s, off, 64);
    if (d == 0) ratings[b] = 1.0f / (1.0f + expf(-s));
}

// ---------------------------------------------------------------------------
extern "C" void kernel_launch(void* const* d_in, const int* in_sizes, int n_in,
                              void* d_out, int out_size, void* d_ws, size_t ws_size,
                              hipStream_t stream) {
    const float* user_emb  = (const float*)d_in[0];
    const float* item_emb  = (const float*)d_in[1];
    const float* edge_vals = (const float*)d_in[2];
    const int*   edge_src  = (const int*)d_in[3];
    const int*   edge_dst  = (const int*)d_in[4];
    const int*   users     = (const int*)d_in[5];
    const int*   items     = (const int*)d_in[6];

    float* out          = (float*)d_out;
    float* ratings      = out;                       // [BATCH]
    float* inter        = out + BATCH;               // [BATCH, DIM]
    float* inter_layers = out + BATCH + BATCH * DIM; // [BATCH, 4, DIM]

    const size_t node_buf_bytes = (size_t)N_NODES * DIM * sizeof(float); // 256 MB
    char* ws = (char*)d_ws;
    size_t off = 0;
    float* bufA = (float*)(ws + off); off += node_buf_bytes;
    float* bufB = (float*)(ws + off); off += node_buf_bytes;
    int* row_ptr   = (int*)(ws + off); off += (size_t)(N_NODES + 16) * sizeof(int);
    int* deg_fill  = (int*)(ws + off); off += (size_t)N_NODES * sizeof(int);  // deg, then fill
    int* csr_src   = (int*)(ws + off); off += (size_t)N_EDGES * sizeof(int);
    float* csr_val = (float*)(ws + off); off += (size_t)N_EDGES * sizeof(float);
    int* blockSums = (int*)(ws + off); off += 1024 * sizeof(int);
    float* u_sum   = (float*)(ws + off); off += (size_t)BATCH * DIM * sizeof(float);
    float* i_sum   = (float*)(ws + off); off += (size_t)BATCH * DIM * sizeof(float);

    const dim3 blk(256);
    const dim3 egrid((N_EDGES + 255) / 256);
    const dim3 ngrid((N_NODES + 255) / 256);
    const dim3 spmm_grid((N_NODES * 16 + 255) / 256);
    const dim3 ext_grid(BATCH / 4);

    // --- CSR build (once; reused by all 3 layers) ---
    hipMemsetAsync(deg_fill, 0, (size_t)N_NODES * sizeof(int), stream);
    hist_kernel<<<egrid, blk, 0, stream>>>(edge_dst, deg_fill);
    scan1_kernel<<<NB_SCAN, blk, 0, stream>>>(deg_fill, row_ptr, blockSums);
    scan2_kernel<<<1, 1024, 0, stream>>>(blockSums);
    scan3_kernel<<<ngrid, blk, 0, stream>>>(row_ptr, blockSums, deg_fill);  // deg_fill -> fill
    scatter_kernel<<<egrid, blk, 0, stream>>>(edge_vals, edge_src, edge_dst,
                                              deg_fill, csr_src, csr_val);

    // --- layer 0 extraction (original embeddings, inits sums) ---
    extract_layer_kernel<<<ext_grid, blk, 0, stream>>>(
        user_emb, item_emb, users, items, inter_layers, u_sum, i_sum, 0);

    // --- layer 1: inputs -> bufA ---
    spmm_csr_kernel<<<spmm_grid, blk, 0, stream>>>(
        user_emb, item_emb, row_ptr, csr_src, csr_val, bufA);
    extract_layer_kernel<<<ext_grid, blk, 0, stream>>>(
        bufA, bufA + (size_t)N_USER * DIM, users, items, inter_layers, u_sum, i_sum, 1);

    // --- layer 2: bufA -> bufB ---
    spmm_csr_kernel<<<spmm_grid, blk, 0, stream>>>(
        bufA, bufA + (size_t)N_USER * DIM, row_ptr, csr_src, csr_val, bufB);
    extract_layer_kernel<<<ext_grid, blk, 0, stream>>>(
        bufB, bufB + (size_t)N_USER * DIM, users, items, inter_layers, u_sum, i_sum, 2);

    // --- layer 3: bufB -> bufA ---
    spmm_csr_kernel<<<spmm_grid, blk, 0, stream>>>(
        bufB, bufB + (size_t)N_USER * DIM, row_ptr, csr_src, csr_val, bufA);
    extract_layer_kernel<<<ext_grid, blk, 0, stream>>>(
        bufA, bufA + (size_t)N_USER * DIM, users, items, inter_layers, u_sum, i_sum, 3);

    // --- pooling + ratings ---
    finalize_kernel<<<ext_grid, blk, 0, stream>>>(u_sum, i_sum, ratings, inter);
}